// Round 1
// baseline (25939.368 us; speedup 1.0000x reference)
//
#include <hip/hip_runtime.h>

#define NEG_SLOPE 0.2f

// ---------------------------------------------------------------------------
// K1: per-node  h1 = x @ W1 (6 -> 24), plus attention logits
//     as1[n,h] = sum_c h1[n,h,c] * att_src1[h,c];  ad1 likewise
// ---------------------------------------------------------------------------
__global__ void k1_node1(const float* __restrict__ x,
                         const float* __restrict__ W1,
                         const float* __restrict__ asw,
                         const float* __restrict__ adw,
                         float* __restrict__ h1,
                         float* __restrict__ as1,
                         float* __restrict__ ad1,
                         int N)
{
    int n = blockIdx.x * blockDim.x + threadIdx.x;
    if (n >= N) return;
    float xv[6];
#pragma unroll
    for (int k = 0; k < 6; ++k) xv[k] = x[n * 6 + k];
#pragma unroll
    for (int h = 0; h < 4; ++h) {
        float as = 0.f, ad = 0.f;
#pragma unroll
        for (int c = 0; c < 6; ++c) {
            int j = h * 6 + c;
            float v = 0.f;
#pragma unroll
            for (int k = 0; k < 6; ++k) v += xv[k] * W1[k * 24 + j];
            h1[n * 24 + j] = v;
            as += v * asw[j];
            ad += v * adw[j];
        }
        as1[n * 4 + h] = as;
        ad1[n * 4 + h] = ad;
    }
}

// ---------------------------------------------------------------------------
// K2: edge pass, layer 1.  For each edge (incl. implicit self-loops at the
// end): w = exp(leaky(as[src]+ad[dst])); atomically accumulate denominator
// and weighted source features into per-dst accumulators.
// (max-subtraction of the reference softmax cancels in num/den -> skipped)
// ---------------------------------------------------------------------------
__global__ void k2_edge1(const int* __restrict__ src,
                         const int* __restrict__ dst,
                         const float* __restrict__ as1,
                         const float* __restrict__ ad1,
                         const float* __restrict__ h1,
                         float* __restrict__ den1,
                         float* __restrict__ acc1,
                         int E, int N)
{
    int i = blockIdx.x * blockDim.x + threadIdx.x;
    int tot = E + N;
    if (i >= tot) return;
    int s, d;
    if (i < E) { s = src[i]; d = dst[i]; }
    else       { s = d = i - E; }
#pragma unroll
    for (int h = 0; h < 4; ++h) {
        float e = as1[s * 4 + h] + ad1[d * 4 + h];
        e = e > 0.f ? e : NEG_SLOPE * e;
        float w = expf(e);
        unsafeAtomicAdd(&den1[d * 4 + h], w);
#pragma unroll
        for (int c = 0; c < 6; ++c)
            unsafeAtomicAdd(&acc1[d * 24 + h * 6 + c], w * h1[s * 24 + h * 6 + c]);
    }
}

// ---------------------------------------------------------------------------
// K3: normalize layer-1 output, ReLU, then per-node GEMM (24 -> 120) with W2
// staged in LDS, plus layer-2 attention logits.
// ---------------------------------------------------------------------------
__global__ void k3_node2(const float* __restrict__ acc1,
                         const float* __restrict__ den1,
                         const float* __restrict__ b1,
                         const float* __restrict__ W2,
                         const float* __restrict__ asw2,
                         const float* __restrict__ adw2,
                         float* __restrict__ h2,
                         float* __restrict__ as2,
                         float* __restrict__ ad2,
                         int N)
{
    __shared__ float Wl[24 * 120];
    for (int t = threadIdx.x; t < 24 * 120; t += blockDim.x) Wl[t] = W2[t];
    __syncthreads();

    int n = blockIdx.x * blockDim.x + threadIdx.x;
    if (n >= N) return;

    float hr[24];
#pragma unroll
    for (int j = 0; j < 24; ++j) {
        int h = j / 6;
        float v = acc1[n * 24 + j] / (den1[n * 4 + h] + 1e-16f) + b1[j];
        hr[j] = v > 0.f ? v : 0.f;
    }
    float as[4] = {0.f, 0.f, 0.f, 0.f};
    float ad[4] = {0.f, 0.f, 0.f, 0.f};
    for (int j = 0; j < 120; ++j) {
        float v = 0.f;
#pragma unroll
        for (int k = 0; k < 24; ++k) v += hr[k] * Wl[k * 120 + j];
        h2[n * 120 + j] = v;
        int h = j / 30;
        as[h] += v * asw2[j];
        ad[h] += v * adw2[j];
    }
#pragma unroll
    for (int h = 0; h < 4; ++h) {
        as2[n * 4 + h] = as[h];
        ad2[n * 4 + h] = ad[h];
    }
}

// ---------------------------------------------------------------------------
// K4: edge pass, layer 2.  4 threads per edge (one per head); each thread
// accumulates its head's 30-wide weighted feature vector + denominator.
// ---------------------------------------------------------------------------
__global__ void k4_edge2(const int* __restrict__ src,
                         const int* __restrict__ dst,
                         const float* __restrict__ as2,
                         const float* __restrict__ ad2,
                         const float* __restrict__ h2,
                         float* __restrict__ den2,
                         float* __restrict__ acc2,
                         int E, int N)
{
    long long t = (long long)blockIdx.x * blockDim.x + threadIdx.x;
    int tot = E + N;
    int i = (int)(t >> 2);
    if (i >= tot) return;
    int h = (int)(t & 3);
    int s, d;
    if (i < E) { s = src[i]; d = dst[i]; }
    else       { s = d = i - E; }
    float e = as2[s * 4 + h] + ad2[d * 4 + h];
    e = e > 0.f ? e : NEG_SLOPE * e;
    float w = expf(e);
    unsafeAtomicAdd(&den2[d * 4 + h], w);
    const float* hp = h2 + (long long)s * 120 + h * 30;
    float* ap = acc2 + (long long)d * 120 + h * 30;
#pragma unroll
    for (int c = 0; c < 30; ++c)
        unsafeAtomicAdd(&ap[c], w * hp[c]);
}

// ---------------------------------------------------------------------------
// K5: per-head normalize, mean over heads, +b2, ReLU, fused MLP 30->15->2.
// ---------------------------------------------------------------------------
__global__ void k5_mlp(const float* __restrict__ acc2,
                       const float* __restrict__ den2,
                       const float* __restrict__ b2,
                       const float* __restrict__ fw1,
                       const float* __restrict__ fb1,
                       const float* __restrict__ fw2,
                       const float* __restrict__ fb2,
                       float* __restrict__ out,
                       int N)
{
    int n = blockIdx.x * blockDim.x + threadIdx.x;
    if (n >= N) return;
    float inv[4];
#pragma unroll
    for (int h = 0; h < 4; ++h) inv[h] = 0.25f / (den2[n * 4 + h] + 1e-16f);
    float z[30];
#pragma unroll
    for (int c = 0; c < 30; ++c) {
        float v = 0.f;
#pragma unroll
        for (int h = 0; h < 4; ++h) v += acc2[n * 120 + h * 30 + c] * inv[h];
        v += b2[c];
        z[c] = v > 0.f ? v : 0.f;
    }
    float m[15];
#pragma unroll
    for (int j = 0; j < 15; ++j) {
        float v = fb1[j];
#pragma unroll
        for (int c = 0; c < 30; ++c) v += z[c] * fw1[c * 15 + j];
        m[j] = v > 0.f ? v : 0.f;
    }
#pragma unroll
    for (int k = 0; k < 2; ++k) {
        float v = fb2[k];
#pragma unroll
        for (int j = 0; j < 15; ++j) v += m[j] * fw2[j * 2 + k];
        out[n * 2 + k] = v;
    }
}

// ---------------------------------------------------------------------------
extern "C" void kernel_launch(void* const* d_in, const int* in_sizes, int n_in,
                              void* d_out, int out_size, void* d_ws, size_t ws_size,
                              hipStream_t stream)
{
    const float* x    = (const float*)d_in[0];
    const int*   ei   = (const int*)  d_in[1];
    // d_in[2] = edge_attr (ignored: edge_dim=None)
    const float* w1   = (const float*)d_in[3];
    const float* as1w = (const float*)d_in[4];
    const float* ad1w = (const float*)d_in[5];
    const float* b1   = (const float*)d_in[6];
    const float* w2   = (const float*)d_in[7];
    const float* as2w = (const float*)d_in[8];
    const float* ad2w = (const float*)d_in[9];
    const float* b2   = (const float*)d_in[10];
    const float* fw1  = (const float*)d_in[11];
    const float* fb1  = (const float*)d_in[12];
    const float* fw2  = (const float*)d_in[13];
    const float* fb2  = (const float*)d_in[14];

    const int N = in_sizes[0] / 6;
    const int E = in_sizes[1] / 2;
    const int* src = ei;
    const int* dst = ei + E;

    float* ws = (float*)d_ws;
    size_t off = 0;
    float* h1   = ws + off; off += (size_t)N * 24;
    float* as1  = ws + off; off += (size_t)N * 4;
    float* ad1  = ws + off; off += (size_t)N * 4;
    float* h2   = ws + off; off += (size_t)N * 120;
    float* as2  = ws + off; off += (size_t)N * 4;
    float* ad2  = ws + off; off += (size_t)N * 4;
    float* zreg = ws + off;                         // zeroed region start
    float* den1 = ws + off; off += (size_t)N * 4;
    float* acc1 = ws + off; off += (size_t)N * 24;
    float* den2 = ws + off; off += (size_t)N * 4;
    float* acc2 = ws + off; off += (size_t)N * 120;
    // total ws usage: 312 * N floats (~125 MB at N=100k)

    hipMemsetAsync(zreg, 0, (size_t)N * 152 * sizeof(float), stream);

    const int B = 256;
    k1_node1<<<(N + B - 1) / B, B, 0, stream>>>(x, w1, as1w, ad1w, h1, as1, ad1, N);

    const int tot = E + N;
    k2_edge1<<<(tot + B - 1) / B, B, 0, stream>>>(src, dst, as1, ad1, h1, den1, acc1, E, N);

    k3_node2<<<(N + B - 1) / B, B, 0, stream>>>(acc1, den1, b1, w2, as2w, ad2w,
                                                h2, as2, ad2, N);

    const long long tot4 = (long long)tot * 4;
    k4_edge2<<<(int)((tot4 + B - 1) / B), B, 0, stream>>>(src, dst, as2, ad2, h2,
                                                          den2, acc2, E, N);

    k5_mlp<<<(N + B - 1) / B, B, 0, stream>>>(acc2, den2, b2, fw1, fb1, fw2, fb2,
                                              (float*)d_out, N);
}

// Round 2
// 1067.275 us; speedup vs baseline: 24.3043x; 24.3043x over previous
//
#include <hip/hip_runtime.h>

#define NEG_SLOPE 0.2f

// ===========================================================================
// CSR build: degree histogram -> exclusive scan (3 small kernels) -> scatter
// ===========================================================================
__global__ void k_deg(const int* __restrict__ dst, int* __restrict__ deg, int E)
{
    int i = blockIdx.x * blockDim.x + threadIdx.x;
    if (i >= E) return;
    atomicAdd(&deg[dst[i]], 1);
}

__global__ void k_scanA(const int* __restrict__ deg, int* __restrict__ bsum, int N)
{
    __shared__ int sm[256];
    int t = threadIdx.x;
    int i = blockIdx.x * 256 + t;
    sm[t] = (i < N) ? deg[i] : 0;
    __syncthreads();
    for (int off = 128; off > 0; off >>= 1) {
        if (t < off) sm[t] += sm[t + off];
        __syncthreads();
    }
    if (t == 0) bsum[blockIdx.x] = sm[0];
}

// single block scans up to 512 block sums (N <= 131072 with 256-blocks)
__global__ void k_scanB(const int* __restrict__ bsum, int* __restrict__ bofs, int NB)
{
    __shared__ int sm[512];
    int t = threadIdx.x;
    int v = (t < NB) ? bsum[t] : 0;
    sm[t] = v;
    __syncthreads();
    for (int off = 1; off < 512; off <<= 1) {
        int x = (t >= off) ? sm[t - off] : 0;
        __syncthreads();
        sm[t] += x;
        __syncthreads();
    }
    if (t < NB) bofs[t] = sm[t] - v;   // exclusive
}

__global__ void k_scanC(const int* __restrict__ deg, const int* __restrict__ bofs,
                        int* __restrict__ rowp, int N)
{
    __shared__ int sm[256];
    int t = threadIdx.x;
    int i = blockIdx.x * 256 + t;
    int v = (i < N) ? deg[i] : 0;
    sm[t] = v;
    __syncthreads();
    for (int off = 1; off < 256; off <<= 1) {
        int x = (t >= off) ? sm[t - off] : 0;
        __syncthreads();
        sm[t] += x;
        __syncthreads();
    }
    if (i < N) rowp[i] = bofs[blockIdx.x] + sm[t] - v;   // exclusive global
}

__global__ void k_scatter(const int* __restrict__ src, const int* __restrict__ dst,
                          const int* __restrict__ rowp, int* __restrict__ cursor,
                          int* __restrict__ esrc, int E)
{
    int i = blockIdx.x * blockDim.x + threadIdx.x;
    if (i >= E) return;
    int d = dst[i];
    int pos = atomicAdd(&cursor[d], 1);
    esrc[rowp[d] + pos] = src[i];
}

// ===========================================================================
// K1: per-node h1 = x @ W1 (6 -> 24) + attention logits as1/ad1
// ===========================================================================
__global__ void k1_node1(const float* __restrict__ x,
                         const float* __restrict__ W1,
                         const float* __restrict__ asw,
                         const float* __restrict__ adw,
                         float* __restrict__ h1,
                         float* __restrict__ as1,
                         float* __restrict__ ad1,
                         int N)
{
    int n = blockIdx.x * blockDim.x + threadIdx.x;
    if (n >= N) return;
    float xv[6];
#pragma unroll
    for (int k = 0; k < 6; ++k) xv[k] = x[n * 6 + k];
#pragma unroll
    for (int h = 0; h < 4; ++h) {
        float as = 0.f, ad = 0.f;
#pragma unroll
        for (int c = 0; c < 6; ++c) {
            int j = h * 6 + c;
            float v = 0.f;
#pragma unroll
            for (int k = 0; k < 6; ++k) v += xv[k] * W1[k * 24 + j];
            h1[n * 24 + j] = v;
            as += v * asw[j];
            ad += v * adw[j];
        }
        as1[n * 4 + h] = as;
        ad1[n * 4 + h] = ad;
    }
}

// ===========================================================================
// Gather layer 1: one thread per (node, head). Register accumulation,
// no atomics. Includes implicit self-loop. Writes relu(acc/den + b1).
// ===========================================================================
__global__ void k_gather1(const int* __restrict__ rowp, const int* __restrict__ deg,
                          const int* __restrict__ esrc,
                          const float* __restrict__ as1, const float* __restrict__ ad1,
                          const float* __restrict__ h1, const float* __restrict__ b1,
                          float* __restrict__ g1, int N)
{
    int t = blockIdx.x * blockDim.x + threadIdx.x;
    int n = t >> 2;
    if (n >= N) return;
    int h = t & 3;
    float adn = ad1[n * 4 + h];

    // self loop
    float e0 = as1[n * 4 + h] + adn;
    e0 = e0 > 0.f ? e0 : NEG_SLOPE * e0;
    float w = expf(e0);
    float den = w;
    float acc[6];
    const float* hp = h1 + (size_t)n * 24 + h * 6;
#pragma unroll
    for (int c = 0; c < 6; ++c) acc[c] = w * hp[c];

    int start = rowp[n], cnt = deg[n];
    for (int k = 0; k < cnt; ++k) {
        int s = esrc[start + k];
        float e = as1[s * 4 + h] + adn;
        e = e > 0.f ? e : NEG_SLOPE * e;
        w = expf(e);
        den += w;
        const float* sp = h1 + (size_t)s * 24 + h * 6;
#pragma unroll
        for (int c = 0; c < 6; ++c) acc[c] += w * sp[c];
    }
    float inv = 1.f / (den + 1e-16f);
#pragma unroll
    for (int c = 0; c < 6; ++c) {
        float v = acc[c] * inv + b1[h * 6 + c];
        g1[(size_t)n * 24 + h * 6 + c] = v > 0.f ? v : 0.f;
    }
}

// ===========================================================================
// K3: per-node GEMM g1 (24) @ W2 (24x120) with W2 in LDS + layer-2 logits
// ===========================================================================
__global__ void k3_node2(const float* __restrict__ g1,
                         const float* __restrict__ W2,
                         const float* __restrict__ asw2,
                         const float* __restrict__ adw2,
                         float* __restrict__ h2,
                         float* __restrict__ as2,
                         float* __restrict__ ad2,
                         int N)
{
    __shared__ float Wl[24 * 120];
    for (int t = threadIdx.x; t < 24 * 120; t += blockDim.x) Wl[t] = W2[t];
    __syncthreads();

    int n = blockIdx.x * blockDim.x + threadIdx.x;
    if (n >= N) return;

    float hr[24];
#pragma unroll
    for (int j = 0; j < 24; ++j) hr[j] = g1[(size_t)n * 24 + j];

    float as[4] = {0.f, 0.f, 0.f, 0.f};
    float ad[4] = {0.f, 0.f, 0.f, 0.f};
    for (int j = 0; j < 120; ++j) {
        float v = 0.f;
#pragma unroll
        for (int k = 0; k < 24; ++k) v += hr[k] * Wl[k * 120 + j];
        h2[(size_t)n * 120 + j] = v;
        int h = j / 30;
        as[h] += v * asw2[j];
        ad[h] += v * adw2[j];
    }
#pragma unroll
    for (int h = 0; h < 4; ++h) {
        as2[n * 4 + h] = as[h];
        ad2[n * 4 + h] = ad[h];
    }
}

// ===========================================================================
// Gather layer 2: ONE WAVE PER NODE. Lane l owns channels l and l+64 of the
// 120 (heads of 30). Each edge's h2[src] read is a coalesced 480B line.
// Head-mean done in-register via shuffles; writes z[N,30] (pre-bias).
// ===========================================================================
__global__ void k_gather2(const int* __restrict__ rowp, const int* __restrict__ deg,
                          const int* __restrict__ esrc,
                          const float* __restrict__ as2, const float* __restrict__ ad2,
                          const float* __restrict__ h2,
                          float* __restrict__ z, int N)
{
    int wid = threadIdx.x >> 6;
    int lane = threadIdx.x & 63;
    int n = blockIdx.x * (blockDim.x >> 6) + wid;
    if (n >= N) return;

    int jA = lane;
    int jB = lane + 64;
    int hA = jA / 30;                 // 0..2
    bool okB = (jB < 120);
    int hB = okB ? jB / 30 : 3;

    float adA = ad2[n * 4 + hA];
    float adB = ad2[n * 4 + hB];

    // self loop
    float eA = as2[n * 4 + hA] + adA; eA = eA > 0.f ? eA : NEG_SLOPE * eA;
    float eB = as2[n * 4 + hB] + adB; eB = eB > 0.f ? eB : NEG_SLOPE * eB;
    float wA = expf(eA), wB = expf(eB);
    float denA = wA, denB = wB;
    const float* hpn = h2 + (size_t)n * 120;
    float accA = wA * hpn[jA];
    float accB = okB ? wB * hpn[jB] : 0.f;

    int start = rowp[n], cnt = deg[n];
    for (int k = 0; k < cnt; ++k) {
        int s = esrc[start + k];
        float aA = as2[s * 4 + hA] + adA; aA = aA > 0.f ? aA : NEG_SLOPE * aA;
        float aB = as2[s * 4 + hB] + adB; aB = aB > 0.f ? aB : NEG_SLOPE * aB;
        float vwA = expf(aA);
        float vwB = expf(aB);
        const float* sp = h2 + (size_t)s * 120;
        accA += vwA * sp[jA];
        denA += vwA;
        if (okB) accB += vwB * sp[jB];
        denB += vwB;
    }
    float vA = accA / (denA + 1e-16f);
    float vB = okB ? accB / (denB + 1e-16f) : 0.f;

    // head mean for channels c = lane < 30:
    //   c (own vA), c+30 (vA of lane+30), c+60 (vA lane+60 if c<4 else vB lane-4),
    //   c+90 (vB of lane+26)
    float s1 = __shfl(vA, lane + 30, 64);
    float s2 = __shfl(vA, lane + 60, 64);   // valid only for lane<4
    float s3 = __shfl(vB, lane - 4, 64);    // valid for 4<=lane<30
    float s4 = __shfl(vB, lane + 26, 64);
    if (lane < 30) {
        float t3 = (lane < 4) ? s2 : s3;
        z[(size_t)n * 30 + lane] = 0.25f * (vA + s1 + t3 + s4);
    }
}

// ===========================================================================
// K5: +b2, ReLU, fused MLP 30 -> 15 -> 2
// ===========================================================================
__global__ void k5_mlp(const float* __restrict__ z,
                       const float* __restrict__ b2,
                       const float* __restrict__ fw1,
                       const float* __restrict__ fb1,
                       const float* __restrict__ fw2,
                       const float* __restrict__ fb2,
                       float* __restrict__ out,
                       int N)
{
    int n = blockIdx.x * blockDim.x + threadIdx.x;
    if (n >= N) return;
    float zz[30];
#pragma unroll
    for (int c = 0; c < 30; ++c) {
        float v = z[(size_t)n * 30 + c] + b2[c];
        zz[c] = v > 0.f ? v : 0.f;
    }
    float m[15];
#pragma unroll
    for (int j = 0; j < 15; ++j) {
        float v = fb1[j];
#pragma unroll
        for (int c = 0; c < 30; ++c) v += zz[c] * fw1[c * 15 + j];
        m[j] = v > 0.f ? v : 0.f;
    }
#pragma unroll
    for (int k = 0; k < 2; ++k) {
        float v = fb2[k];
#pragma unroll
        for (int j = 0; j < 15; ++j) v += m[j] * fw2[j * 2 + k];
        out[n * 2 + k] = v;
    }
}

// ===========================================================================
extern "C" void kernel_launch(void* const* d_in, const int* in_sizes, int n_in,
                              void* d_out, int out_size, void* d_ws, size_t ws_size,
                              hipStream_t stream)
{
    const float* x    = (const float*)d_in[0];
    const int*   ei   = (const int*)  d_in[1];
    // d_in[2] = edge_attr (ignored)
    const float* w1   = (const float*)d_in[3];
    const float* as1w = (const float*)d_in[4];
    const float* ad1w = (const float*)d_in[5];
    const float* b1   = (const float*)d_in[6];
    const float* w2   = (const float*)d_in[7];
    const float* as2w = (const float*)d_in[8];
    const float* ad2w = (const float*)d_in[9];
    const float* b2   = (const float*)d_in[10];
    const float* fw1  = (const float*)d_in[11];
    const float* fb1  = (const float*)d_in[12];
    const float* fw2  = (const float*)d_in[13];
    const float* fb2  = (const float*)d_in[14];

    const int N = in_sizes[0] / 6;
    const int E = in_sizes[1] / 2;
    const int* src = ei;
    const int* dst = ei + E;

    float* ws = (float*)d_ws;
    size_t off = 0;
    float* h1  = ws + off; off += (size_t)N * 24;
    float* as1 = ws + off; off += (size_t)N * 4;
    float* ad1 = ws + off; off += (size_t)N * 4;
    float* g1  = ws + off; off += (size_t)N * 24;
    float* h2  = ws + off; off += (size_t)N * 120;
    float* as2 = ws + off; off += (size_t)N * 4;
    float* ad2 = ws + off; off += (size_t)N * 4;
    float* z   = ws + off; off += (size_t)N * 30;

    int* iw = (int*)(ws + off);
    size_t ioff = 0;
    int* rowp   = iw + ioff; ioff += N;
    int* bsum   = iw + ioff; ioff += 512;
    int* bofs   = iw + ioff; ioff += 512;
    int* esrc   = iw + ioff; ioff += E;
    int* deg    = iw + ioff; ioff += N;   // zeroed (deg, cursor contiguous)
    int* cursor = iw + ioff; ioff += N;   // zeroed
    // total ~100 MB of d_ws

    hipMemsetAsync(deg, 0, (size_t)2 * N * sizeof(int), stream);

    const int B = 256;
    const int NB = (N + B - 1) / B;     // <= 512 for N <= 131072

    // CSR build
    k_deg    <<<(E + B - 1) / B, B, 0, stream>>>(dst, deg, E);
    k_scanA  <<<NB, B, 0, stream>>>(deg, bsum, N);
    k_scanB  <<<1, 512, 0, stream>>>(bsum, bofs, NB);
    k_scanC  <<<NB, B, 0, stream>>>(deg, bofs, rowp, N);
    k_scatter<<<(E + B - 1) / B, B, 0, stream>>>(src, dst, rowp, cursor, esrc, E);

    // layer 1
    k1_node1 <<<NB, B, 0, stream>>>(x, w1, as1w, ad1w, h1, as1, ad1, N);
    k_gather1<<<(N * 4 + B - 1) / B, B, 0, stream>>>(rowp, deg, esrc, as1, ad1,
                                                     h1, b1, g1, N);
    // layer 2
    k3_node2 <<<NB, B, 0, stream>>>(g1, w2, as2w, ad2w, h2, as2, ad2, N);
    k_gather2<<<(N + 3) / 4, B, 0, stream>>>(rowp, deg, esrc, as2, ad2, h2, z, N);

    // head
    k5_mlp   <<<NB, B, 0, stream>>>(z, b2, fw1, fb1, fw2, fb2, (float*)d_out, N);
}

// Round 3
// 613.208 us; speedup vs baseline: 42.3011x; 1.7405x over previous
//
#include <hip/hip_runtime.h>

#define NEG_SLOPE 0.2f

// ===========================================================================
// CSR build: degree histogram -> exclusive scan (3 small kernels) -> scatter
// ===========================================================================
__global__ void k_deg(const int* __restrict__ dst, int* __restrict__ deg, int E)
{
    int i = blockIdx.x * blockDim.x + threadIdx.x;
    if (i >= E) return;
    atomicAdd(&deg[dst[i]], 1);
}

__global__ void k_scanA(const int* __restrict__ deg, int* __restrict__ bsum, int N)
{
    __shared__ int sm[256];
    int t = threadIdx.x;
    int i = blockIdx.x * 256 + t;
    sm[t] = (i < N) ? deg[i] : 0;
    __syncthreads();
    for (int off = 128; off > 0; off >>= 1) {
        if (t < off) sm[t] += sm[t + off];
        __syncthreads();
    }
    if (t == 0) bsum[blockIdx.x] = sm[0];
}

// single block scans up to 512 block sums (N <= 131072 with 256-blocks)
__global__ void k_scanB(const int* __restrict__ bsum, int* __restrict__ bofs, int NB)
{
    __shared__ int sm[512];
    int t = threadIdx.x;
    int v = (t < NB) ? bsum[t] : 0;
    sm[t] = v;
    __syncthreads();
    for (int off = 1; off < 512; off <<= 1) {
        int x = (t >= off) ? sm[t - off] : 0;
        __syncthreads();
        sm[t] += x;
        __syncthreads();
    }
    if (t < NB) bofs[t] = sm[t] - v;   // exclusive
}

__global__ void k_scanC(const int* __restrict__ deg, const int* __restrict__ bofs,
                        int* __restrict__ rowp, int N)
{
    __shared__ int sm[256];
    int t = threadIdx.x;
    int i = blockIdx.x * 256 + t;
    int v = (i < N) ? deg[i] : 0;
    sm[t] = v;
    __syncthreads();
    for (int off = 1; off < 256; off <<= 1) {
        int x = (t >= off) ? sm[t - off] : 0;
        __syncthreads();
        sm[t] += x;
        __syncthreads();
    }
    if (i < N) rowp[i] = bofs[blockIdx.x] + sm[t] - v;   // exclusive global
}

__global__ void k_scatter(const int* __restrict__ src, const int* __restrict__ dst,
                          const int* __restrict__ rowp, int* __restrict__ cursor,
                          int* __restrict__ esrc, int E)
{
    int i = blockIdx.x * blockDim.x + threadIdx.x;
    if (i >= E) return;
    int d = dst[i];
    int pos = atomicAdd(&cursor[d], 1);
    esrc[rowp[d] + pos] = src[i];
}

// ===========================================================================
// Fold attention vectors through the layer weights (240 outputs):
//  fold[0..24)    asv1[h][k] = sum_c W1[k,24: h*6+c] * att_src1[h,c]   (k<6)
//  fold[24..48)   adv1
//  fold[48..144)  asv2[h][k] = sum_c W2[k,120: h*30+c] * att_src2[h,c] (k<24)
//  fold[144..240) adv2
// ===========================================================================
__global__ void k_fold(const float* __restrict__ W1,
                       const float* __restrict__ s1, const float* __restrict__ d1,
                       const float* __restrict__ W2,
                       const float* __restrict__ s2, const float* __restrict__ d2,
                       float* __restrict__ fold)
{
    int t = threadIdx.x;
    if (t < 24) {
        int h = t / 6, k = t % 6;
        float v = 0.f;
        for (int c = 0; c < 6; ++c) v += W1[k * 24 + h * 6 + c] * s1[h * 6 + c];
        fold[t] = v;
    } else if (t < 48) {
        int u = t - 24, h = u / 6, k = u % 6;
        float v = 0.f;
        for (int c = 0; c < 6; ++c) v += W1[k * 24 + h * 6 + c] * d1[h * 6 + c];
        fold[t] = v;
    } else if (t < 144) {
        int u = t - 48, h = u / 24, k = u % 24;
        float v = 0.f;
        for (int c = 0; c < 30; ++c) v += W2[k * 120 + h * 30 + c] * s2[h * 30 + c];
        fold[t] = v;
    } else if (t < 240) {
        int u = t - 144, h = u / 24, k = u % 24;
        float v = 0.f;
        for (int c = 0; c < 30; ++c) v += W2[k * 120 + h * 30 + c] * d2[h * 30 + c];
        fold[t] = v;
    }
}

// ===========================================================================
// K1: layer-1 attention logits directly from x: as1[n,h] = x[n] . asv1[h]
// ===========================================================================
__global__ void k1_logits(const float* __restrict__ x,
                          const float* __restrict__ fold,
                          float* __restrict__ as1, float* __restrict__ ad1, int N)
{
    int n = blockIdx.x * blockDim.x + threadIdx.x;
    if (n >= N) return;
    float xv[6];
#pragma unroll
    for (int k = 0; k < 6; ++k) xv[k] = x[n * 6 + k];
#pragma unroll
    for (int h = 0; h < 4; ++h) {
        float as = 0.f, ad = 0.f;
#pragma unroll
        for (int k = 0; k < 6; ++k) {
            as += xv[k] * fold[h * 6 + k];
            ad += xv[k] * fold[24 + h * 6 + k];
        }
        as1[n * 4 + h] = as;
        ad1[n * 4 + h] = ad;
    }
}

// ===========================================================================
// Gather layer 1 in x-space (6-dim). One thread per (node, head); quads of
// lanes share the same node so their x[s] loads coalesce/merge. Projects
// through W1_h per node at the end. Writes g1 = relu(m @ W1_h + b1_h).
// ===========================================================================
__global__ void k_gather1(const int* __restrict__ rowp, const int* __restrict__ deg,
                          const int* __restrict__ esrc,
                          const float* __restrict__ x,
                          const float* __restrict__ as1, const float* __restrict__ ad1,
                          const float* __restrict__ W1, const float* __restrict__ b1,
                          float* __restrict__ g1, int N)
{
    int t = blockIdx.x * blockDim.x + threadIdx.x;
    int n = t >> 2;
    if (n >= N) return;
    int h = t & 3;
    float adn = ad1[n * 4 + h];

    // self loop
    float e0 = as1[n * 4 + h] + adn;
    e0 = e0 > 0.f ? e0 : NEG_SLOPE * e0;
    float w = expf(e0);
    float den = w;
    float acc[6];
    {
        const float2* xp = (const float2*)(x + (size_t)n * 6);
        float2 a = xp[0], b = xp[1], c = xp[2];
        acc[0] = w * a.x; acc[1] = w * a.y; acc[2] = w * b.x;
        acc[3] = w * b.y; acc[4] = w * c.x; acc[5] = w * c.y;
    }
    int start = rowp[n], cnt = deg[n];
    for (int k = 0; k < cnt; ++k) {
        int s = esrc[start + k];
        float e = as1[s * 4 + h] + adn;
        e = e > 0.f ? e : NEG_SLOPE * e;
        w = expf(e);
        den += w;
        const float2* xp = (const float2*)(x + (size_t)s * 6);
        float2 a = xp[0], b = xp[1], c = xp[2];
        acc[0] += w * a.x; acc[1] += w * a.y; acc[2] += w * b.x;
        acc[3] += w * b.y; acc[4] += w * c.x; acc[5] += w * c.y;
    }
    float inv = 1.f / (den + 1e-16f);
    float m[6];
#pragma unroll
    for (int k = 0; k < 6; ++k) m[k] = acc[k] * inv;
#pragma unroll
    for (int c = 0; c < 6; ++c) {
        float v = b1[h * 6 + c];
#pragma unroll
        for (int k = 0; k < 6; ++k) v += m[k] * W1[k * 24 + h * 6 + c];
        g1[(size_t)n * 24 + h * 6 + c] = v > 0.f ? v : 0.f;
    }
}

// ===========================================================================
// K3: layer-2 logits from g1 with folded vectors: as2[n,h] = g1[n] . asv2[h]
// ===========================================================================
__global__ void k3_logits(const float* __restrict__ g1,
                          const float* __restrict__ fold,
                          float* __restrict__ as2, float* __restrict__ ad2, int N)
{
    int n = blockIdx.x * blockDim.x + threadIdx.x;
    if (n >= N) return;
    float g[24];
    const float4* gp = (const float4*)(g1 + (size_t)n * 24);
#pragma unroll
    for (int q = 0; q < 6; ++q) {
        float4 v = gp[q];
        g[q * 4 + 0] = v.x; g[q * 4 + 1] = v.y; g[q * 4 + 2] = v.z; g[q * 4 + 3] = v.w;
    }
#pragma unroll
    for (int h = 0; h < 4; ++h) {
        float as = 0.f, ad = 0.f;
#pragma unroll
        for (int k = 0; k < 24; ++k) {
            as += g[k] * fold[48 + h * 24 + k];
            ad += g[k] * fold[144 + h * 24 + k];
        }
        as2[n * 4 + h] = as;
        ad2[n * 4 + h] = ad;
    }
}

// ===========================================================================
// Gather layer 2 in g1-space (24-dim), one thread per (node, head). Quads
// merge g1[s] loads. Epilogue: project m@W2_h (24->30), quad shfl-xor
// head-sum, then lane h==0 does mean + b2 + relu + fused MLP 30->15->2.
// ===========================================================================
__global__ void k_gather2(const int* __restrict__ rowp, const int* __restrict__ deg,
                          const int* __restrict__ esrc,
                          const float* __restrict__ g1,
                          const float* __restrict__ as2, const float* __restrict__ ad2,
                          const float* __restrict__ W2, const float* __restrict__ b2,
                          const float* __restrict__ fw1, const float* __restrict__ fb1,
                          const float* __restrict__ fw2, const float* __restrict__ fb2,
                          float* __restrict__ out, int N)
{
    int t = blockIdx.x * blockDim.x + threadIdx.x;
    int n = t >> 2;
    if (n >= N) return;
    int h = t & 3;
    float adn = ad2[n * 4 + h];

    float acc[24];
    // self loop
    float e0 = as2[n * 4 + h] + adn;
    e0 = e0 > 0.f ? e0 : NEG_SLOPE * e0;
    float w = expf(e0);
    float den = w;
    {
        const float4* gp = (const float4*)(g1 + (size_t)n * 24);
#pragma unroll
        for (int q = 0; q < 6; ++q) {
            float4 v = gp[q];
            acc[q * 4 + 0] = w * v.x; acc[q * 4 + 1] = w * v.y;
            acc[q * 4 + 2] = w * v.z; acc[q * 4 + 3] = w * v.w;
        }
    }
    int start = rowp[n], cnt = deg[n];
    for (int k = 0; k < cnt; ++k) {
        int s = esrc[start + k];
        float e = as2[s * 4 + h] + adn;
        e = e > 0.f ? e : NEG_SLOPE * e;
        w = expf(e);
        den += w;
        const float4* gp = (const float4*)(g1 + (size_t)s * 24);
#pragma unroll
        for (int q = 0; q < 6; ++q) {
            float4 v = gp[q];
            acc[q * 4 + 0] += w * v.x; acc[q * 4 + 1] += w * v.y;
            acc[q * 4 + 2] += w * v.z; acc[q * 4 + 3] += w * v.w;
        }
    }
    float inv = 1.f / (den + 1e-16f);
#pragma unroll
    for (int k = 0; k < 24; ++k) acc[k] *= inv;

    // project to 30 channels of this head, sum across the 4 heads (quad lanes)
    float zz[30];
#pragma unroll
    for (int c = 0; c < 30; ++c) {
        float v = 0.f;
#pragma unroll
        for (int k = 0; k < 24; ++k) v += acc[k] * W2[k * 120 + h * 30 + c];
        v += __shfl_xor(v, 1);
        v += __shfl_xor(v, 2);
        zz[c] = v;          // full head-sum on all 4 lanes
    }
    if (h == 0) {
#pragma unroll
        for (int c = 0; c < 30; ++c) {
            float v = 0.25f * zz[c] + b2[c];
            zz[c] = v > 0.f ? v : 0.f;
        }
        float m2[15];
#pragma unroll
        for (int j = 0; j < 15; ++j) {
            float v = fb1[j];
#pragma unroll
            for (int c = 0; c < 30; ++c) v += zz[c] * fw1[c * 15 + j];
            m2[j] = v > 0.f ? v : 0.f;
        }
#pragma unroll
        for (int k = 0; k < 2; ++k) {
            float v = fb2[k];
#pragma unroll
            for (int j = 0; j < 15; ++j) v += m2[j] * fw2[j * 2 + k];
            out[(size_t)n * 2 + k] = v;
        }
    }
}

// ===========================================================================
extern "C" void kernel_launch(void* const* d_in, const int* in_sizes, int n_in,
                              void* d_out, int out_size, void* d_ws, size_t ws_size,
                              hipStream_t stream)
{
    const float* x    = (const float*)d_in[0];
    const int*   ei   = (const int*)  d_in[1];
    // d_in[2] = edge_attr (ignored)
    const float* w1   = (const float*)d_in[3];
    const float* as1w = (const float*)d_in[4];
    const float* ad1w = (const float*)d_in[5];
    const float* b1   = (const float*)d_in[6];
    const float* w2   = (const float*)d_in[7];
    const float* as2w = (const float*)d_in[8];
    const float* ad2w = (const float*)d_in[9];
    const float* b2   = (const float*)d_in[10];
    const float* fw1  = (const float*)d_in[11];
    const float* fb1  = (const float*)d_in[12];
    const float* fw2  = (const float*)d_in[13];
    const float* fb2  = (const float*)d_in[14];

    const int N = in_sizes[0] / 6;
    const int E = in_sizes[1] / 2;
    const int* src = ei;
    const int* dst = ei + E;

    float* ws = (float*)d_ws;
    size_t off = 0;
    float* as1  = ws + off; off += (size_t)N * 4;
    float* ad1  = ws + off; off += (size_t)N * 4;
    float* g1   = ws + off; off += (size_t)N * 24;
    float* as2  = ws + off; off += (size_t)N * 4;
    float* ad2  = ws + off; off += (size_t)N * 4;
    float* fold = ws + off; off += 256;

    int* iw = (int*)(ws + off);
    size_t ioff = 0;
    int* rowp   = iw + ioff; ioff += N;
    int* bsum   = iw + ioff; ioff += 512;
    int* bofs   = iw + ioff; ioff += 512;
    int* esrc   = iw + ioff; ioff += E;
    int* deg    = iw + ioff; ioff += N;   // zeroed (deg, cursor contiguous)
    int* cursor = iw + ioff; ioff += N;   // zeroed
    // total ~31 MB of d_ws

    hipMemsetAsync(deg, 0, (size_t)2 * N * sizeof(int), stream);

    const int B = 256;
    const int NB = (N + B - 1) / B;     // <= 512 for N <= 131072
    const int EB = (E + B - 1) / B;
    const int QB = (N * 4 + B - 1) / B;

    k_fold   <<<1, 256, 0, stream>>>(w1, as1w, ad1w, w2, as2w, ad2w, fold);

    // CSR build
    k_deg    <<<EB, B, 0, stream>>>(dst, deg, E);
    k_scanA  <<<NB, B, 0, stream>>>(deg, bsum, N);
    k_scanB  <<<1, 512, 0, stream>>>(bsum, bofs, NB);
    k_scanC  <<<NB, B, 0, stream>>>(deg, bofs, rowp, N);
    k_scatter<<<EB, B, 0, stream>>>(src, dst, rowp, cursor, esrc, E);

    // layer 1 (aggregate in 6-dim x-space, project through W1 after)
    k1_logits<<<NB, B, 0, stream>>>(x, fold, as1, ad1, N);
    k_gather1<<<QB, B, 0, stream>>>(rowp, deg, esrc, x, as1, ad1, w1, b1, g1, N);

    // layer 2 (aggregate in 24-dim g1-space, project through W2 after) + MLP
    k3_logits<<<NB, B, 0, stream>>>(g1, fold, as2, ad2, N);
    k_gather2<<<QB, B, 0, stream>>>(rowp, deg, esrc, g1, as2, ad2, w2, b2,
                                    fw1, fb1, fw2, fb2, (float*)d_out, N);
}